// Round 5
// baseline (30.837 us; speedup 1.0000x reference)
//
#include <hip/hip_runtime.h>
#include <math.h>

#define NVIEWS 4
#define DIM 2048
#define CLAMP_MIN_F 0.0005f
#define CLAMP_MAX_F 0.9995f
#define NORM_EPS_F 1e-12f

// One wave (64 lanes) per chunk of 4 rows, 4 waves/block, 1024 blocks
// (= 4 blocks/CU, 16 waves/CU). 3-buffer software pipeline: 12 float4 loads
// (12 KiB/wave) in flight, FMAs run 2 iterations behind the load front.
// All buffer indices are compile-time (macro-expanded) so everything stays
// in registers. Two-kernel structure on purpose: last-block atomic fusion
// measured 102 us (1024 same-address device-scope atomics serialize).
__global__ __launch_bounds__(256, 4) void chunk_loss_kernel(
    const float* __restrict__ x, float* __restrict__ partials, int C)
{
    const int lane  = threadIdx.x & 63;
    const int wave  = threadIdx.x >> 6;
    const int chunk = blockIdx.x * 4 + wave;

    // acc index map: 0:(0,0) 1:(0,1) 2:(0,2) 3:(0,3) 4:(1,1) 5:(1,2)
    //                6:(1,3) 7:(2,2) 8:(2,3) 9:(3,3)
    float acc[10];
#pragma unroll
    for (int p = 0; p < 10; ++p) acc[p] = 0.0f;

    if (chunk < C) {
        const float* base = x + (size_t)chunk * (NVIEWS * DIM) + lane * 4;
        float b0[4][4], b1[4][4], b2[4][4];

#define LOADB(BUF, IT)                                                     \
        {                                                                  \
            _Pragma("unroll")                                              \
            for (int i = 0; i < 4; ++i)                                    \
                *reinterpret_cast<float4*>(BUF[i]) =                       \
                    *reinterpret_cast<const float4*>(base + i * DIM + (IT) * 256); \
        }
#define FMAB(BUF)                                                          \
        {                                                                  \
            int p = 0;                                                     \
            _Pragma("unroll")                                              \
            for (int i = 0; i < 4; ++i)                                    \
                _Pragma("unroll")                                          \
                for (int j = i; j < 4; ++j, ++p)                           \
                    _Pragma("unroll")                                      \
                    for (int k = 0; k < 4; ++k)                            \
                        acc[p] = fmaf(BUF[i][k], BUF[j][k], acc[p]);       \
        }

        LOADB(b0, 0)
        LOADB(b1, 1)
        LOADB(b2, 2)
        FMAB(b0)  LOADB(b0, 3)
        FMAB(b1)  LOADB(b1, 4)
        FMAB(b2)  LOADB(b2, 5)
        FMAB(b0)  LOADB(b0, 6)
        FMAB(b1)  LOADB(b1, 7)
        FMAB(b2)
        FMAB(b0)
        FMAB(b1)
#undef LOADB
#undef FMAB
    }

    // wave-level butterfly reduction across 64 lanes
#pragma unroll
    for (int p = 0; p < 10; ++p) {
#pragma unroll
        for (int s = 32; s > 0; s >>= 1)
            acc[p] += __shfl_xor(acc[p], s, 64);
    }

    __shared__ float lds[4];
    float loss = 0.0f;
    if (lane == 0) {
        if (chunk < C) {
            const float n0 = fmaxf(sqrtf(acc[0]), NORM_EPS_F);
            const float n1 = fmaxf(sqrtf(acc[4]), NORM_EPS_F);
            const float n2 = fmaxf(sqrtf(acc[7]), NORM_EPS_F);
            const float n3 = fmaxf(sqrtf(acc[9]), NORM_EPS_F);
            const float i0 = 1.0f / n0, i1 = 1.0f / n1;
            const float i2 = 1.0f / n2, i3 = 1.0f / n3;
            float sum = 0.0f, s;
#define TERM(P, IA, IB, W)                                        \
            s = acc[P] * (IA) * (IB);                             \
            s = fminf(fmaxf(s, CLAMP_MIN_F), CLAMP_MAX_F);        \
            sum += (W) * (-__logf(1.0f - s));
            TERM(0, i0, i0, 1.0f)   // diagonal
            TERM(4, i1, i1, 1.0f)
            TERM(7, i2, i2, 1.0f)
            TERM(9, i3, i3, 1.0f)
            TERM(1, i0, i1, 2.0f)   // off-diagonal pairs, counted twice
            TERM(2, i0, i2, 2.0f)
            TERM(3, i0, i3, 2.0f)
            TERM(5, i1, i2, 2.0f)
            TERM(6, i1, i3, 2.0f)
            TERM(8, i2, i3, 2.0f)
#undef TERM
            loss = sum * (1.0f / 16.0f);
        }
        lds[wave] = loss;
    }
    __syncthreads();
    if (threadIdx.x == 0)
        partials[blockIdx.x] = lds[0] + lds[1] + lds[2] + lds[3];
}

// Minimal deterministic final reduction: one wave, float4 loads.
__global__ __launch_bounds__(64) void reduce_kernel(
    const float* __restrict__ partials, float* __restrict__ out, int n)
{
    float s = 0.0f;
    for (int i = threadIdx.x * 4; i < n; i += 64 * 4) {
        const float4 v = *reinterpret_cast<const float4*>(partials + i);
        s += (v.x + v.y) + (v.z + v.w);
    }
#pragma unroll
    for (int d = 32; d > 0; d >>= 1) s += __shfl_xor(s, d, 64);
    if (threadIdx.x == 0) out[0] = s;
}

extern "C" void kernel_launch(void* const* d_in, const int* in_sizes, int n_in,
                              void* d_out, int out_size, void* d_ws, size_t ws_size,
                              hipStream_t stream)
{
    const float* x = (const float*)d_in[0];
    float* out = (float*)d_out;
    float* partials = (float*)d_ws;   // nblocks floats (4 KiB)

    const int total  = in_sizes[0];
    const int C      = total / (NVIEWS * DIM);   // 4096 chunks
    const int blocks = (C + 3) / 4;              // 1024 blocks

    chunk_loss_kernel<<<blocks, 256, 0, stream>>>(x, partials, C);
    reduce_kernel<<<1, 64, 0, stream>>>(partials, out, blocks);
}

// Round 6
// 29.846 us; speedup vs baseline: 1.0332x; 1.0332x over previous
//
#include <hip/hip_runtime.h>
#include <math.h>

#define NVIEWS 4
#define DIM 2048
#define CLAMP_MIN_F 0.0005f
#define CLAMP_MAX_F 0.9995f
#define NORM_EPS_F 1e-12f

// One wave (64 lanes) per chunk of 4 rows, 4 waves/block, 1024 blocks
// (= 4 blocks/CU, 16 waves/CU — structurally max: 4096 waves / 256 CU).
// 3-buffer software pipeline, 12 float4 loads (12 KiB/wave) in flight.
// Two-kernel structure on purpose: last-block atomic fusion measured 102 us
// (1024 same-address device-scope fence+atomic ops serialize ~80ns each).
__global__ __launch_bounds__(256, 4) void chunk_loss_kernel(
    const float* __restrict__ x, float* __restrict__ partials, int C)
{
    const int lane  = threadIdx.x & 63;
    const int wave  = threadIdx.x >> 6;
    const int chunk = blockIdx.x * 4 + wave;

    // acc index map: 0:(0,0) 1:(0,1) 2:(0,2) 3:(0,3) 4:(1,1) 5:(1,2)
    //                6:(1,3) 7:(2,2) 8:(2,3) 9:(3,3)
    float acc[10];
#pragma unroll
    for (int p = 0; p < 10; ++p) acc[p] = 0.0f;

    if (chunk < C) {
        const float* base = x + (size_t)chunk * (NVIEWS * DIM) + lane * 4;
        float b0[4][4], b1[4][4], b2[4][4];

#define LOADB(BUF, IT)                                                     \
        {                                                                  \
            _Pragma("unroll")                                              \
            for (int i = 0; i < 4; ++i)                                    \
                *reinterpret_cast<float4*>(BUF[i]) =                       \
                    *reinterpret_cast<const float4*>(base + i * DIM + (IT) * 256); \
        }
#define FMAB(BUF)                                                          \
        {                                                                  \
            int p = 0;                                                     \
            _Pragma("unroll")                                              \
            for (int i = 0; i < 4; ++i)                                    \
                _Pragma("unroll")                                          \
                for (int j = i; j < 4; ++j, ++p)                           \
                    _Pragma("unroll")                                      \
                    for (int k = 0; k < 4; ++k)                            \
                        acc[p] = fmaf(BUF[i][k], BUF[j][k], acc[p]);       \
        }

        LOADB(b0, 0)
        LOADB(b1, 1)
        LOADB(b2, 2)
        FMAB(b0)  LOADB(b0, 3)
        FMAB(b1)  LOADB(b1, 4)
        FMAB(b2)  LOADB(b2, 5)
        FMAB(b0)  LOADB(b0, 6)
        FMAB(b1)  LOADB(b1, 7)
        FMAB(b2)
        FMAB(b0)
        FMAB(b1)
#undef LOADB
#undef FMAB
    }

    // wave-level butterfly reduction across 64 lanes
#pragma unroll
    for (int p = 0; p < 10; ++p) {
#pragma unroll
        for (int s = 32; s > 0; s >>= 1)
            acc[p] += __shfl_xor(acc[p], s, 64);
    }

    __shared__ float lds[4];
    float loss = 0.0f;
    if (lane == 0) {
        if (chunk < C) {
            const float n0 = fmaxf(sqrtf(acc[0]), NORM_EPS_F);
            const float n1 = fmaxf(sqrtf(acc[4]), NORM_EPS_F);
            const float n2 = fmaxf(sqrtf(acc[7]), NORM_EPS_F);
            const float n3 = fmaxf(sqrtf(acc[9]), NORM_EPS_F);
            const float i0 = 1.0f / n0, i1 = 1.0f / n1;
            const float i2 = 1.0f / n2, i3 = 1.0f / n3;
            float sum = 0.0f, s;
#define TERM(P, IA, IB, W)                                        \
            s = acc[P] * (IA) * (IB);                             \
            s = fminf(fmaxf(s, CLAMP_MIN_F), CLAMP_MAX_F);        \
            sum += (W) * (-__logf(1.0f - s));
            TERM(0, i0, i0, 1.0f)   // diagonal
            TERM(4, i1, i1, 1.0f)
            TERM(7, i2, i2, 1.0f)
            TERM(9, i3, i3, 1.0f)
            TERM(1, i0, i1, 2.0f)   // off-diagonal pairs, counted twice
            TERM(2, i0, i2, 2.0f)
            TERM(3, i0, i3, 2.0f)
            TERM(5, i1, i2, 2.0f)
            TERM(6, i1, i3, 2.0f)
            TERM(8, i2, i3, 2.0f)
#undef TERM
            loss = sum * (1.0f / 16.0f);
        }
        lds[wave] = loss;
    }
    __syncthreads();
    if (threadIdx.x == 0)
        partials[blockIdx.x] = lds[0] + lds[1] + lds[2] + lds[3];
}

// Final reduction, minimal latency chain: 256 threads, each loads exactly
// one float4 (single vmem round-trip), 6-stage shuffle, 4-way LDS combine.
__global__ __launch_bounds__(256) void reduce_kernel(
    const float4* __restrict__ partials4, float* __restrict__ out, int n4)
{
    const int tid = threadIdx.x;
    float s = 0.0f;
    if (tid < n4) {
        const float4 v = partials4[tid];
        s = (v.x + v.y) + (v.z + v.w);
    }
#pragma unroll
    for (int d = 32; d > 0; d >>= 1) s += __shfl_xor(s, d, 64);
    __shared__ float lds[4];
    if ((tid & 63) == 0) lds[tid >> 6] = s;
    __syncthreads();
    if (tid == 0) out[0] = lds[0] + lds[1] + lds[2] + lds[3];
}

extern "C" void kernel_launch(void* const* d_in, const int* in_sizes, int n_in,
                              void* d_out, int out_size, void* d_ws, size_t ws_size,
                              hipStream_t stream)
{
    const float* x = (const float*)d_in[0];
    float* out = (float*)d_out;
    float* partials = (float*)d_ws;   // nblocks floats (4 KiB)

    const int total  = in_sizes[0];
    const int C      = total / (NVIEWS * DIM);   // 4096 chunks
    const int blocks = (C + 3) / 4;              // 1024 blocks

    chunk_loss_kernel<<<blocks, 256, 0, stream>>>(x, partials, C);
    reduce_kernel<<<1, 256, 0, stream>>>((const float4*)partials, out, blocks / 4);
}